// Round 2
// baseline (224.688 us; speedup 1.0000x reference)
//
#include <hip/hip_runtime.h>

#define NQ     32
#define NGATES 62
#define DP     496    // 32*31/2
#define BATCH  4096

// idx(a,b) = frow(a) + b for a<b, with frow(p) = 30p - p(p-1)/2 - 1
__device__ __host__ __forceinline__ constexpr int frow(int p) {
    return 30 * p - (p * (p - 1)) / 2 - 1;
}

__global__ void rbs_cs_kernel(const float* __restrict__ ang, float* __restrict__ cs) {
    int t = threadIdx.x;
    if (t < NGATES) {
        float s, c;
        __sincosf(ang[t], &s, &c);          // fast path ok: |ang| < 1, but use precise:
        sincosf(ang[t], &s, &c);            // keep precise result (overwrites)
        cs[2 * t]     = c;
        cs[2 * t + 1] = s;
    }
}

__global__ __launch_bounds__(256, 2) void rbs_main_kernel(
        const float* __restrict__ in,
        const float* __restrict__ cs,
        float* __restrict__ out) {
    const int tid  = threadIdx.x;
    const int wave = tid >> 6;        // 0..3
    const int lane = tid & 63;
    const int h    = lane >> 5;       // half: which element of this wave's pair
    const int c    = lane & 31;       // column owned by this lane

    // Per-wave private LDS slice. Staging area and transpose area overlap in
    // time-disjoint phases; same-wave DS ops execute in order (no barrier).
    __shared__ __align__(16) float lds[4][2112];
    float* wbuf = lds[wave];

    const int e0 = blockIdx.x * 8 + wave * 2;   // first element of this wave
    const int e  = e0 + h;                      // this half's element

    // ---- stage 2*496 contiguous input floats, coalesced float4 ----
    {
        const float4* src = reinterpret_cast<const float4*>(in + (size_t)e0 * DP);
        float4*       dst = reinterpret_cast<float4*>(wbuf);
#pragma unroll
        for (int i = 0; i < 4; ++i) {
            int k = i * 64 + lane;
            if (k < (2 * DP) / 4) dst[k] = src[k];
        }
    }

    // ---- build column A[:,c] in registers (A antisymmetric, A[p][c]) ----
    const float* sh = wbuf + h * DP;
    const int fc = 30 * c - (c * (c - 1)) / 2 - 1;   // frow(c), runtime

    float a[NQ];
#pragma unroll
    for (int p = 0; p < NQ; ++p) {
        int addr = (p < c) ? (frow(p) + c) : (fc + p);
        if (p == c) addr = 0;                 // avoid OOB (-1) when p==c==0
        float v = sh[addr];
        float r = (p < c) ? v : -v;           // A[p][c] = s(p,c) if p<c else -s(c,p)
        a[p] = (p == c) ? 0.f : r;
    }

    // ---- pass 1: a := Q a   (column c of D = Q A); gates g=(i,i+1) ----
#pragma unroll
    for (int g = 0; g < NGATES; ++g) {
        const int i = (g < 31) ? g : (g - 31);
        const float cg = cs[2 * g];
        const float sg = cs[2 * g + 1];
        const float x = a[i], y = a[i + 1];
        a[i]     = cg * x + sg * y;
        a[i + 1] = cg * y - sg * x;
    }

    // ---- in-wave transpose via LDS ([32][33] pad => conflict-free) ----
    // write row c: mh[c][q] = a[q] = D[q][c]; read col c: a[q] = mh[q][c] = D[c][q]
    float* mh = wbuf + h * 1056;   // [32][33]
#pragma unroll
    for (int q = 0; q < NQ; ++q) mh[c * 33 + q] = a[q];
#pragma unroll
    for (int q = 0; q < NQ; ++q) a[q] = mh[q * 33 + c];

    // ---- pass 2: a := Q a   (E[:,c] = Q (D^T)[:,c]);  A_out = -E ----
#pragma unroll
    for (int g = 0; g < NGATES; ++g) {
        const int i = (g < 31) ? g : (g - 31);
        const float cg = cs[2 * g];
        const float sg = cs[2 * g + 1];
        const float x = a[i], y = a[i + 1];
        a[i]     = cg * x + sg * y;
        a[i + 1] = cg * y - sg * x;
    }

    // ---- store upper triangle: s'_(p,c) = A_out[p][c] = -a[p], p < c ----
    // For fixed p, addresses frow(p)+c are consecutive across lanes -> coalesced.
    float* op = out + (size_t)e * DP;
#pragma unroll
    for (int p = 0; p < NQ - 1; ++p) {
        if (p < c) op[frow(p) + c] = -a[p];
    }
}

extern "C" void kernel_launch(void* const* d_in, const int* in_sizes, int n_in,
                              void* d_out, int out_size, void* d_ws, size_t ws_size,
                              hipStream_t stream) {
    const float* in  = (const float*)d_in[0];   // [4096, 496] fp32
    const float* ang = (const float*)d_in[1];   // [62] fp32
    // d_in[2] (U, [62,3,496,496] = 183 MB) is intentionally never read.
    float* out = (float*)d_out;                 // [4096, 496] fp32
    float* cs  = (float*)d_ws;                  // 124 floats scratch

    rbs_cs_kernel<<<1, 64, 0, stream>>>(ang, cs);
    rbs_main_kernel<<<BATCH / 8, 256, 0, stream>>>(in, cs, out);
}

// Round 3
// 220.740 us; speedup vs baseline: 1.0179x; 1.0179x over previous
//
#include <hip/hip_runtime.h>

#define NQ     32
#define NGATES 62
#define DP     496    // 32*31/2
#define BATCH  4096

// idx(a,b) = frow(a) + b for a<b, with frow(p) = 30p - p(p-1)/2 - 1
__device__ __host__ __forceinline__ constexpr int frow(int p) {
    return 30 * p - (p * (p - 1)) / 2 - 1;
}

// Single fused kernel: per-block sincos prep (62 angles -> LDS broadcast),
// then per-lane Givens-rotation evolution of the antisymmetric state matrix.
// Math: state s over weight-2 basis <-> antisymmetric A (A[a][b]=s_(a,b), a<b);
// each RBS gate is A <- G A G^T with G the 32x32 Givens rotation. With
// Q = G61...G0:  D = QA (pass 1, per-column), A_out = Q(D^T)*(-1) (pass 2,
// using antisymmetry: A Q^T = -(QA)^T).
__global__ __launch_bounds__(256, 2) void rbs_fused_kernel(
        const float* __restrict__ in,
        const float* __restrict__ ang,
        float* __restrict__ out) {
    const int tid  = threadIdx.x;
    const int wave = tid >> 6;        // 0..3
    const int lane = tid & 63;
    const int h    = lane >> 5;       // half: which element of this wave's pair
    const int c    = lane & 31;       // column owned by this lane

    // Per-wave private LDS slice. Staging area and transpose area overlap in
    // time-disjoint phases; same-wave DS ops execute in order (no barrier
    // needed for wave-private data). cs_sh needs the one __syncthreads.
    __shared__ __align__(16) float lds[4][2112];
    __shared__ __align__(16) float cs_sh[2 * NGATES];
    float* wbuf = lds[wave];

    // ---- phase 0: 62 sincos into LDS (uniform broadcast table) ----
    if (tid < NGATES) {
        float s, cthv;
        sincosf(ang[tid], &s, &cthv);
        cs_sh[2 * tid]     = cthv;
        cs_sh[2 * tid + 1] = s;
    }

    const int e0 = blockIdx.x * 8 + wave * 2;   // first element of this wave
    const int e  = e0 + h;                      // this half's element

    // ---- stage 2*496 contiguous input floats, coalesced float4 ----
    {
        const float4* src = reinterpret_cast<const float4*>(in + (size_t)e0 * DP);
        float4*       dst = reinterpret_cast<float4*>(wbuf);
#pragma unroll
        for (int i = 0; i < 4; ++i) {
            int k = i * 64 + lane;
            if (k < (2 * DP) / 4) dst[k] = src[k];
        }
    }

    __syncthreads();   // cs_sh ready (also orders nothing else: lds[] is wave-private)

    // ---- build column A[:,c] in registers (A antisymmetric) ----
    const float* sh = wbuf + h * DP;
    const int fc = 30 * c - (c * (c - 1)) / 2 - 1;   // frow(c), runtime

    float a[NQ];
#pragma unroll
    for (int p = 0; p < NQ; ++p) {
        int addr = (p < c) ? (frow(p) + c) : (fc + p);
        if (p == c) addr = 0;                 // avoid OOB (-1) when p==c==0
        float v = sh[addr];
        float r = (p < c) ? v : -v;           // A[p][c] = s(p,c) if p<c else -s(c,p)
        a[p] = (p == c) ? 0.f : r;
    }

    const float2* cs2 = reinterpret_cast<const float2*>(cs_sh);

    // ---- pass 1: a := Q a   (column c of D = Q A); gates g=(i,i+1) ----
#pragma unroll
    for (int g = 0; g < NGATES; ++g) {
        const int i = (g < 31) ? g : (g - 31);
        const float2 t = cs2[g];              // ds_read_b64, same-address broadcast
        const float x = a[i], y = a[i + 1];
        a[i]     = t.x * x + t.y * y;
        a[i + 1] = t.x * y - t.y * x;
    }

    // ---- in-wave transpose via LDS ([32][33] pad => conflict-free) ----
    float* mh = wbuf + h * 1056;   // [32][33]
#pragma unroll
    for (int q = 0; q < NQ; ++q) mh[c * 33 + q] = a[q];
#pragma unroll
    for (int q = 0; q < NQ; ++q) a[q] = mh[q * 33 + c];

    // ---- pass 2: a := Q a   (E[:,c] = Q (D^T)[:,c]);  A_out = -E ----
#pragma unroll
    for (int g = 0; g < NGATES; ++g) {
        const int i = (g < 31) ? g : (g - 31);
        const float2 t = cs2[g];
        const float x = a[i], y = a[i + 1];
        a[i]     = t.x * x + t.y * y;
        a[i + 1] = t.x * y - t.y * x;
    }

    // ---- store upper triangle: s'_(p,c) = A_out[p][c] = -a[p], p < c ----
    // For fixed p, addresses frow(p)+c are consecutive across lanes -> coalesced.
    float* op = out + (size_t)e * DP;
#pragma unroll
    for (int p = 0; p < NQ - 1; ++p) {
        if (p < c) op[frow(p) + c] = -a[p];
    }
}

extern "C" void kernel_launch(void* const* d_in, const int* in_sizes, int n_in,
                              void* d_out, int out_size, void* d_ws, size_t ws_size,
                              hipStream_t stream) {
    const float* in  = (const float*)d_in[0];   // [4096, 496] fp32
    const float* ang = (const float*)d_in[1];   // [62] fp32
    // d_in[2] (U, [62,3,496,496] = 183 MB) is intentionally never read.
    float* out = (float*)d_out;                 // [4096, 496] fp32
    (void)d_ws; (void)ws_size;

    rbs_fused_kernel<<<BATCH / 8, 256, 0, stream>>>(in, ang, out);
}